// Round 1
// baseline (2612.541 us; speedup 1.0000x reference)
//
#include <hip/hip_runtime.h>
#include <hip/hip_bf16.h>
#include <cstdint>

#define DM   1024      // d_model
#define NH   16        // heads
#define DEP  64        // depth per head
#define BB   2         // batch
#define SS   2048      // seq len
#define ROWS (BB*SS)   // 4096

// ---------------------------------------------------------------------------
// Generic  Y = X @ W + bias.   X:[ROWS,DM] row-major, W:[DM,DM] row-major.
// head_layout=1 -> write Y to [B,H,S,DEP] ; head_layout=0 -> [ROWS,DM].
// Tile 64x64, BK=16, 256 threads, 4x4 micro-tile per thread.
// ---------------------------------------------------------------------------
__global__ __launch_bounds__(256)
void gemm_xw(const float* __restrict__ X, const float* __restrict__ W,
             const float* __restrict__ bias, float* __restrict__ out,
             int head_layout)
{
    __shared__ float As[16][68];   // [k][m]
    __shared__ float Bs[16][68];   // [k][n]
    const int bm  = blockIdx.x * 64;
    const int bn  = blockIdx.y * 64;
    const int tid = threadIdx.x;
    const int tx  = tid & 15, ty = tid >> 4;
    float acc[4][4] = {};

    for (int k0 = 0; k0 < DM; k0 += 16) {
        // A tile: 64 rows x 16 k   (1024 floats, 4/thread)
        {
            int r  = tid >> 2;             // 0..63
            int c4 = (tid & 3) << 2;       // 0,4,8,12
            float4 av = *(const float4*)(X + (size_t)(bm + r) * DM + k0 + c4);
            As[c4+0][r] = av.x; As[c4+1][r] = av.y;
            As[c4+2][r] = av.z; As[c4+3][r] = av.w;
        }
        // B tile: 16 k x 64 cols
        {
            int br = tid >> 4;             // 0..15
            int bc = (tid & 15) << 2;      // 0..60
            *(float4*)&Bs[br][bc] =
                *(const float4*)(W + (size_t)(k0 + br) * DM + bn + bc);
        }
        __syncthreads();
        #pragma unroll
        for (int kk = 0; kk < 16; ++kk) {
            float a[4], b[4];
            #pragma unroll
            for (int i = 0; i < 4; ++i) a[i] = As[kk][ty*4 + i];
            #pragma unroll
            for (int j = 0; j < 4; ++j) b[j] = Bs[kk][tx*4 + j];
            #pragma unroll
            for (int i = 0; i < 4; ++i)
                #pragma unroll
                for (int j = 0; j < 4; ++j)
                    acc[i][j] = fmaf(a[i], b[j], acc[i][j]);
        }
        __syncthreads();
    }

    #pragma unroll
    for (int i = 0; i < 4; ++i) {
        int row = bm + ty*4 + i;
        int b_  = row >> 11;           // row / 2048
        int s_  = row & 2047;
        #pragma unroll
        for (int j = 0; j < 4; ++j) {
            int col = bn + tx*4 + j;
            float v = acc[i][j] + bias[col];
            if (head_layout) {
                int h = col >> 6, d = col & 63;
                out[(((size_t)(b_*NH + h))*SS + s_)*DEP + d] = v;
            } else {
                out[(size_t)row*DM + col] = v;
            }
        }
    }
}

// ---------------------------------------------------------------------------
// scores = Q K^T / 8, masked (-1e9 where mask==0), written raw to attn buffer.
// Q,K: [B,H,S,DEP].  Tile: 64 q-rows x 64 k-rows, full depth=64 in LDS.
// ---------------------------------------------------------------------------
__global__ __launch_bounds__(256)
void scores_kernel(const float* __restrict__ Q, const float* __restrict__ K,
                   const int* __restrict__ mask, float* __restrict__ attn)
{
    __shared__ float Qs[64][68];
    __shared__ float Ks[64][68];
    const int qt = blockIdx.x * 64;
    const int kt = blockIdx.y * 64;
    const int bh = blockIdx.z;         // b*NH + h
    const int b_ = bh >> 4;
    const float* Qb = Q + (size_t)bh * SS * DEP;
    const float* Kb = K + (size_t)bh * SS * DEP;
    const int tid = threadIdx.x;

    #pragma unroll
    for (int rep = 0; rep < 4; ++rep) {       // 1024 float4 per tile
        int f  = rep*256 + tid;
        int r  = f >> 4;                      // 0..63
        int c4 = (f & 15) << 2;               // 0..60
        *(float4*)&Qs[r][c4] = *(const float4*)(Qb + (size_t)(qt + r)*DEP + c4);
        *(float4*)&Ks[r][c4] = *(const float4*)(Kb + (size_t)(kt + r)*DEP + c4);
    }
    __syncthreads();

    const int tx = tid & 15, ty = tid >> 4;
    float acc[4][4] = {};
    #pragma unroll
    for (int kk = 0; kk < 64; ++kk) {
        float a[4], b[4];
        #pragma unroll
        for (int i = 0; i < 4; ++i) a[i] = Qs[ty*4 + i][kk];
        #pragma unroll
        for (int j = 0; j < 4; ++j) b[j] = Ks[tx*4 + j][kk];
        #pragma unroll
        for (int i = 0; i < 4; ++i)
            #pragma unroll
            for (int j = 0; j < 4; ++j)
                acc[i][j] = fmaf(a[i], b[j], acc[i][j]);
    }

    const float scale = 0.125f;   // 1/sqrt(64)
    #pragma unroll
    for (int i = 0; i < 4; ++i) {
        int qrow = qt + ty*4 + i;
        const int* mrow = mask + (size_t)b_*SS*SS + (size_t)qrow*SS + kt + tx*4;
        int4 mv = *(const int4*)mrow;
        float4 o;
        o.x = mv.x ? acc[i][0]*scale : -1e9f;
        o.y = mv.y ? acc[i][1]*scale : -1e9f;
        o.z = mv.z ? acc[i][2]*scale : -1e9f;
        o.w = mv.w ? acc[i][3]*scale : -1e9f;
        *(float4*)(attn + ((size_t)bh*SS + qrow)*SS + kt + tx*4) = o;
    }
}

// ---------------------------------------------------------------------------
// Row softmax in place.  One block (256 threads) per row of 2048.
// ---------------------------------------------------------------------------
__global__ __launch_bounds__(256)
void softmax_kernel(float* __restrict__ attn)
{
    float* p = attn + (size_t)blockIdx.x * SS;
    const int tid = threadIdx.x;
    float4 v0 = *(const float4*)(p + tid*4);
    float4 v1 = *(const float4*)(p + 1024 + tid*4);

    float m = fmaxf(fmaxf(fmaxf(v0.x, v0.y), fmaxf(v0.z, v0.w)),
                    fmaxf(fmaxf(v1.x, v1.y), fmaxf(v1.z, v1.w)));
    #pragma unroll
    for (int off = 32; off; off >>= 1) m = fmaxf(m, __shfl_down(m, off, 64));

    __shared__ float red[4];
    if ((tid & 63) == 0) red[tid >> 6] = m;
    __syncthreads();
    m = fmaxf(fmaxf(red[0], red[1]), fmaxf(red[2], red[3]));

    float e[8];
    e[0] = __expf(v0.x - m); e[1] = __expf(v0.y - m);
    e[2] = __expf(v0.z - m); e[3] = __expf(v0.w - m);
    e[4] = __expf(v1.x - m); e[5] = __expf(v1.y - m);
    e[6] = __expf(v1.z - m); e[7] = __expf(v1.w - m);
    float s = ((e[0]+e[1]) + (e[2]+e[3])) + ((e[4]+e[5]) + (e[6]+e[7]));
    #pragma unroll
    for (int off = 32; off; off >>= 1) s += __shfl_down(s, off, 64);

    __syncthreads();                       // red reuse
    if ((tid & 63) == 0) red[tid >> 6] = s;
    __syncthreads();
    s = (red[0] + red[1]) + (red[2] + red[3]);
    float inv = 1.0f / s;

    *(float4*)(p + tid*4)        = make_float4(e[0]*inv, e[1]*inv, e[2]*inv, e[3]*inv);
    *(float4*)(p + 1024 + tid*4) = make_float4(e[4]*inv, e[5]*inv, e[6]*inv, e[7]*inv);
}

// ---------------------------------------------------------------------------
// ctx[b,s,h,d] = sum_k attn[b,h,s,k] * V[b,h,k,d].  Tile 64 q-rows, BK=32.
// ---------------------------------------------------------------------------
__global__ __launch_bounds__(256)
void pv_kernel(const float* __restrict__ attn, const float* __restrict__ V,
               float* __restrict__ ctx)
{
    __shared__ float Ps[32][68];   // [k][m]
    __shared__ float Vs[32][68];   // [k][n]
    const int qt = blockIdx.x * 64;
    const int bh = blockIdx.y;
    const int b_ = bh >> 4, h = bh & 15;
    const float* Ab = attn + (size_t)bh * SS * SS;
    const float* Vb = V    + (size_t)bh * SS * DEP;
    const int tid = threadIdx.x;
    const int tx  = tid & 15, ty = tid >> 4;
    float acc[4][4] = {};

    for (int k0 = 0; k0 < SS; k0 += 32) {
        #pragma unroll
        for (int rep = 0; rep < 2; ++rep) {
            int f = rep*256 + tid;            // 0..511
            // P tile: 64 rows x 32 k  (512 float4)
            int r  = f >> 3;                  // 0..63
            int c4 = (f & 7) << 2;            // 0..28
            float4 pv4 = *(const float4*)(Ab + (size_t)(qt + r)*SS + k0 + c4);
            Ps[c4+0][r] = pv4.x; Ps[c4+1][r] = pv4.y;
            Ps[c4+2][r] = pv4.z; Ps[c4+3][r] = pv4.w;
            // V tile: 32 k x 64 d (512 float4)
            int r2  = f >> 4;                 // 0..31
            int c42 = (f & 15) << 2;          // 0..60
            *(float4*)&Vs[r2][c42] =
                *(const float4*)(Vb + (size_t)(k0 + r2)*DEP + c42);
        }
        __syncthreads();
        #pragma unroll
        for (int kk = 0; kk < 32; ++kk) {
            float a[4], b[4];
            #pragma unroll
            for (int i = 0; i < 4; ++i) a[i] = Ps[kk][ty*4 + i];
            #pragma unroll
            for (int j = 0; j < 4; ++j) b[j] = Vs[kk][tx*4 + j];
            #pragma unroll
            for (int i = 0; i < 4; ++i)
                #pragma unroll
                for (int j = 0; j < 4; ++j)
                    acc[i][j] = fmaf(a[i], b[j], acc[i][j]);
        }
        __syncthreads();
    }

    #pragma unroll
    for (int i = 0; i < 4; ++i) {
        int srow = qt + ty*4 + i;
        *(float4*)(ctx + ((size_t)(b_*SS + srow))*DM + h*DEP + tx*4) =
            make_float4(acc[i][0], acc[i][1], acc[i][2], acc[i][3]);
    }
}

// ---------------------------------------------------------------------------
extern "C" void kernel_launch(void* const* d_in, const int* in_sizes, int n_in,
                              void* d_out, int out_size, void* d_ws, size_t ws_size,
                              hipStream_t stream)
{
    const float* query = (const float*)d_in[0];
    const float* key_  = (const float*)d_in[1];
    const float* value = (const float*)d_in[2];
    const int*   mask  = (const int*)  d_in[3];
    const float* Wq = (const float*)d_in[4];  const float* bq = (const float*)d_in[5];
    const float* Wk = (const float*)d_in[6];  const float* bk = (const float*)d_in[7];
    const float* Wv = (const float*)d_in[8];  const float* bv = (const float*)d_in[9];
    const float* Wo = (const float*)d_in[10]; const float* bo = (const float*)d_in[11];

    float* outp = (float*)d_out;                         // [ROWS, DM]
    float* attn = outp + (size_t)ROWS * DM;              // [B,H,S,S]

    float* ws  = (float*)d_ws;
    float* Qw  = ws;                                      // [B,H,S,DEP]
    float* Kw  = Qw + (size_t)ROWS * DM / 1;              // 4,194,304 floats each
    Kw = ws + (size_t)4194304;
    float* Vw  = ws + (size_t)2 * 4194304;
    float* ctx = ws + (size_t)3 * 4194304;                // [B,S,H,DEP] = [ROWS,DM]

    dim3 gemm_grid(ROWS/64, DM/64);        // (64,16)
    gemm_xw<<<gemm_grid, 256, 0, stream>>>(query, Wq, bq, Qw, 1);
    gemm_xw<<<gemm_grid, 256, 0, stream>>>(key_,  Wk, bk, Kw, 1);
    gemm_xw<<<gemm_grid, 256, 0, stream>>>(value, Wv, bv, Vw, 1);

    scores_kernel<<<dim3(SS/64, SS/64, BB*NH), 256, 0, stream>>>(Qw, Kw, mask, attn);
    softmax_kernel<<<BB*NH*SS, 256, 0, stream>>>(attn);
    pv_kernel<<<dim3(SS/64, BB*NH), 256, 0, stream>>>(attn, Vw, ctx);

    gemm_xw<<<gemm_grid, 256, 0, stream>>>(ctx, Wo, bo, outp, 0);
}

// Round 3
// 1318.669 us; speedup vs baseline: 1.9812x; 1.9812x over previous
//
#include <hip/hip_runtime.h>
#include <hip/hip_bf16.h>
#include <cstdint>

#define DM   1024
#define NH   16
#define DEP  64
#define BB   2
#define SS   2048
#define ROWS (BB*SS)

typedef __attribute__((ext_vector_type(8))) short  short8;   // 8 bf16 (4 VGPR)
typedef __attribute__((ext_vector_type(4))) float  f32x4;    // MFMA C/D

#define MFMA_BF16 __builtin_amdgcn_mfma_f32_16x16x32_bf16

// ---------------- helpers ----------------------------------------------------
__device__ __forceinline__ unsigned short f2bf(float x) {   // RNE fp32->bf16
    union { float f; uint32_t u; } v; v.f = x;
    uint32_t r = v.u + 0x7fffu + ((v.u >> 16) & 1u);
    return (unsigned short)(r >> 16);
}
__device__ __forceinline__ float bf2f(unsigned short u) {
    union { uint32_t u; float f; } v; v.u = ((uint32_t)u) << 16;
    return v.f;
}
// async global->LDS, 16B per lane; LDS dest = wave-uniform base + lane*16
__device__ __forceinline__ void gll16(const void* g, void* l) {
    __builtin_amdgcn_global_load_lds(
        (const __attribute__((address_space(1))) void*)g,
        (__attribute__((address_space(3))) void*)l, 16, 0, 0);
}
// XOR swizzle: toggle bits 4..6 by bits 7..9 (involution; keeps 16B alignment)
__device__ __forceinline__ int swz(int o) { return o ^ (((o >> 7) & 7) << 4); }

// ---------------- 1. fp32 -> bf16 hi/lo elementwise --------------------------
__global__ __launch_bounds__(256)
void convx(const float* __restrict__ in, unsigned short* __restrict__ hi,
           unsigned short* __restrict__ lo, int n4) {
    int i = blockIdx.x * 256 + threadIdx.x;
    if (i >= n4) return;
    float4 v = ((const float4*)in)[i];
    ushort4 h, l;
    h.x = f2bf(v.x); l.x = f2bf(v.x - bf2f(h.x));
    h.y = f2bf(v.y); l.y = f2bf(v.y - bf2f(h.y));
    h.z = f2bf(v.z); l.z = f2bf(v.z - bf2f(h.z));
    h.w = f2bf(v.w); l.w = f2bf(v.w - bf2f(h.w));
    ((ushort4*)hi)[i] = h;
    ((ushort4*)lo)[i] = l;
}

// ---------------- 2. W[1024][1024] -> Wt[n][k] bf16 hi/lo (transpose) --------
__global__ __launch_bounds__(256)
void convwt(const float* __restrict__ W, unsigned short* __restrict__ hi,
            unsigned short* __restrict__ lo) {
    __shared__ float t[64][65];
    const int tr = blockIdx.x * 64, tc = blockIdx.y * 64;
    const int tid = threadIdx.x;
    const int r = tid >> 2, c0 = (tid & 3) * 16;
    #pragma unroll
    for (int c = 0; c < 16; c += 4) {
        float4 v = *(const float4*)(W + (size_t)(tr + r) * DM + tc + c0 + c);
        t[r][c0 + c + 0] = v.x; t[r][c0 + c + 1] = v.y;
        t[r][c0 + c + 2] = v.z; t[r][c0 + c + 3] = v.w;
    }
    __syncthreads();
    // Wt[n][k] = W[k][n];  n = tc + r, k = tr + c0 + c
    size_t ob = (size_t)(tc + r) * DM + tr + c0;
    #pragma unroll
    for (int c = 0; c < 16; ++c) {
        float v = t[c0 + c][r];
        unsigned short h = f2bf(v);
        hi[ob + c] = h;
        lo[ob + c] = f2bf(v - bf2f(h));
    }
}

// ---------------- 3. V[bh][s][d] fp32 -> Vt[bh][d][s] bf16 hi/lo -------------
__global__ __launch_bounds__(256)
void convvt(const float* __restrict__ Vf, unsigned short* __restrict__ hi,
            unsigned short* __restrict__ lo) {
    __shared__ float t[64][65];
    const int st = blockIdx.x * 64, bh = blockIdx.y;
    const float* src = Vf + (size_t)bh * SS * DEP;
    const int tid = threadIdx.x;
    const int r = tid >> 2, c0 = (tid & 3) * 16;
    #pragma unroll
    for (int c = 0; c < 16; c += 4) {
        float4 v = *(const float4*)(src + (size_t)(st + r) * DEP + c0 + c);
        t[r][c0 + c + 0] = v.x; t[r][c0 + c + 1] = v.y;
        t[r][c0 + c + 2] = v.z; t[r][c0 + c + 3] = v.w;
    }
    __syncthreads();
    // Vt[d][s]: d = r, s = st + c0 + c; value = V[s][d] = t[c0+c][r]
    size_t ob = ((size_t)bh * DEP + r) * SS + st + c0;
    #pragma unroll
    for (int c = 0; c < 16; ++c) {
        float v = t[c0 + c][r];
        unsigned short h = f2bf(v);
        hi[ob + c] = h;
        lo[ob + c] = f2bf(v - bf2f(h));
    }
}

// ---------------- 4. split-bf16 MFMA GEMM:  Y = X @ W + b --------------------
// X as (Xh,Xl) [4096][1024];  W as transposed (Wth,Wtl) [n][k] [1024][1024].
// variant 0: fp32 row-major out.  1: bf16 hi/lo head layout.  2: fp32 head layout.
__global__ __launch_bounds__(256, 2)
void gemm_split(const unsigned short* __restrict__ Xh, const unsigned short* __restrict__ Xl,
                const unsigned short* __restrict__ Wth, const unsigned short* __restrict__ Wtl,
                const float* __restrict__ bias, float* __restrict__ outf,
                unsigned short* __restrict__ outh, unsigned short* __restrict__ outl,
                int variant) {
    __shared__ unsigned short Ah[4096], Al[4096], Bh[4096], Bl[4096];  // [128][32]
    const int tid = threadIdx.x, lane = tid & 63, wid = tid >> 6;
    const int l15 = lane & 15, g = lane >> 4;
    const int bm = blockIdx.x * 128, bn = blockIdx.y * 128;
    const int wm = wid >> 1, wn = wid & 1;

    // staging geometry (constant over K loop)
    int srow[2], sko[2], ldso[2];
    #pragma unroll
    for (int r = 0; r < 2; ++r) {
        int ch = wid * 2 + r;
        int o  = ch * 1024 + lane * 16;
        int s  = swz(o);
        srow[r] = s >> 6;            // tile row (64B rows)
        sko[r]  = (s & 63) >> 1;     // ushort offset in row
        ldso[r] = ch * 1024;
    }
    // fragment LDS offsets (constant over K loop)
    int aoff[4], boff[4];
    #pragma unroll
    for (int i = 0; i < 4; ++i) {
        aoff[i] = swz((wm * 64 + i * 16 + l15) * 64 + g * 16);
        boff[i] = swz((wn * 64 + i * 16 + l15) * 64 + g * 16);
    }

    f32x4 acc[4][4] = {};
    for (int kt = 0; kt < 32; ++kt) {
        #pragma unroll
        for (int r = 0; r < 2; ++r) {
            size_t ga = (size_t)(bm + srow[r]) * DM + kt * 32 + sko[r];
            size_t gb = (size_t)(bn + srow[r]) * DM + kt * 32 + sko[r];
            gll16(Xh  + ga, (char*)Ah + ldso[r]);
            gll16(Xl  + ga, (char*)Al + ldso[r]);
            gll16(Wth + gb, (char*)Bh + ldso[r]);
            gll16(Wtl + gb, (char*)Bl + ldso[r]);
        }
        __syncthreads();
        short8 afh[4], afl[4], bfh[4], bfl[4];
        #pragma unroll
        for (int i = 0; i < 4; ++i) {
            afh[i] = *(const short8*)((const char*)Ah + aoff[i]);
            afl[i] = *(const short8*)((const char*)Al + aoff[i]);
            bfh[i] = *(const short8*)((const char*)Bh + boff[i]);
            bfl[i] = *(const short8*)((const char*)Bl + boff[i]);
        }
        #pragma unroll
        for (int i = 0; i < 4; ++i)
            #pragma unroll
            for (int j = 0; j < 4; ++j) {
                acc[i][j] = MFMA_BF16(afh[i], bfh[j], acc[i][j], 0, 0, 0);
                acc[i][j] = MFMA_BF16(afl[i], bfh[j], acc[i][j], 0, 0, 0);
                acc[i][j] = MFMA_BF16(afh[i], bfl[j], acc[i][j], 0, 0, 0);
            }
        __syncthreads();
    }
    // epilogue: D layout row=(lane>>4)*4+q, col=lane&15
    #pragma unroll
    for (int i = 0; i < 4; ++i) {
        #pragma unroll
        for (int j = 0; j < 4; ++j) {
            int col = bn + wn * 64 + j * 16 + l15;
            float bv = bias[col];
            #pragma unroll
            for (int q = 0; q < 4; ++q) {
                int row = bm + wm * 64 + i * 16 + g * 4 + q;
                float v = acc[i][j][q] + bv;
                if (variant == 0) {
                    outf[(size_t)row * DM + col] = v;
                } else {
                    int b_ = row >> 11, s_ = row & 2047;
                    int h  = col >> 6,  d  = col & 63;
                    size_t idx = (((size_t)(b_ * NH + h)) * SS + s_) * DEP + d;
                    if (variant == 2) outf[idx] = v;
                    else {
                        unsigned short hb = f2bf(v);
                        outh[idx] = hb;
                        outl[idx] = f2bf(v - bf2f(hb));
                    }
                }
            }
        }
    }
}

// ---------------- 5. fused attention -----------------------------------------
// Per block: (b,h), 128 q-rows.  Pass A: online (m,l).  Pass B: recompute S,
// write normalized P to attn (fp32), accumulate O = P@V via split MFMA.
__global__ __launch_bounds__(256, 2)
void attn_fused(const unsigned short* __restrict__ Qh, const unsigned short* __restrict__ Ql,
                const unsigned short* __restrict__ Kh, const unsigned short* __restrict__ Kl,
                const unsigned short* __restrict__ Vh, const unsigned short* __restrict__ Vl,
                const int* __restrict__ mask, float* __restrict__ attn,
                unsigned short* __restrict__ ctxh, unsigned short* __restrict__ ctxl) {
    __shared__ unsigned short Ksh[4096], Ksl[4096];      // K tile [64 krow][64 d]
    __shared__ unsigned short Vsh[4096], Vsl[4096];      // Vt tile [64 d][64 s]
    __shared__ unsigned short Psh[4][2048], Psl[4][2048];// per-wave P [32 q][64 k]
    const int tid = threadIdx.x, lane = tid & 63, wid = tid >> 6;
    const int l15 = lane & 15, g = lane >> 4;
    const int qt = blockIdx.x * 128, bh = blockIdx.y;
    const int b_ = bh >> 4, h_ = bh & 15;
    const int q0 = qt + wid * 32;

    // Q fragments resident in registers: [m][kstep], hi & lo
    short8 qfh[2][2], qfl[2][2];
    #pragma unroll
    for (int m = 0; m < 2; ++m)
        #pragma unroll
        for (int ks = 0; ks < 2; ++ks) {
            size_t off = ((size_t)bh * SS + q0 + m * 16 + l15) * DEP + ks * 32 + g * 8;
            qfh[m][ks] = *(const short8*)(Qh + off);
            qfl[m][ks] = *(const short8*)(Ql + off);
        }

    // staging geometry (row/offset constant; only kt varies)
    int srow[2], sko[2], ldso[2];
    #pragma unroll
    for (int r = 0; r < 2; ++r) {
        int ch = wid * 2 + r;
        int o  = ch * 1024 + lane * 16;
        int s  = swz(o);
        srow[r] = s >> 7;            // 128B rows
        sko[r]  = (s & 127) >> 1;
        ldso[r] = ch * 1024;
    }
    // K/V fragment LDS offsets (constant)
    int kfo[2][4], pfo[2][2];
    #pragma unroll
    for (int ks = 0; ks < 2; ++ks) {
        #pragma unroll
        for (int n = 0; n < 4; ++n)
            kfo[ks][n] = swz((n * 16 + l15) * 128 + ks * 64 + g * 16);
        #pragma unroll
        for (int m = 0; m < 2; ++m)
            pfo[ks][m] = swz((m * 16 + l15) * 128 + ks * 64 + g * 16);
    }

    const int* mbase = mask + (size_t)b_ * SS * SS;
    float mrun[2][4], lrun[2][4];
    #pragma unroll
    for (int m = 0; m < 2; ++m)
        #pragma unroll
        for (int q = 0; q < 4; ++q) { mrun[m][q] = -1e30f; lrun[m][q] = 0.f; }

    // ---------------- PASS A: stats ----------------
    for (int kt = 0; kt < 32; ++kt) {
        #pragma unroll
        for (int r = 0; r < 2; ++r) {
            size_t gs = ((size_t)bh * SS + kt * 64 + srow[r]) * DEP + sko[r];
            gll16(Kh + gs, (char*)Ksh + ldso[r]);
            gll16(Kl + gs, (char*)Ksl + ldso[r]);
        }
        __syncthreads();
        f32x4 sc[2][4] = {};
        #pragma unroll
        for (int ks = 0; ks < 2; ++ks)
            #pragma unroll
            for (int n = 0; n < 4; ++n) {
                short8 kbh = *(const short8*)((const char*)Ksh + kfo[ks][n]);
                short8 kbl = *(const short8*)((const char*)Ksl + kfo[ks][n]);
                #pragma unroll
                for (int m = 0; m < 2; ++m) {
                    sc[m][n] = MFMA_BF16(qfh[m][ks], kbh, sc[m][n], 0, 0, 0);
                    sc[m][n] = MFMA_BF16(qfl[m][ks], kbh, sc[m][n], 0, 0, 0);
                    sc[m][n] = MFMA_BF16(qfh[m][ks], kbl, sc[m][n], 0, 0, 0);
                }
            }
        #pragma unroll
        for (int m = 0; m < 2; ++m)
            #pragma unroll
            for (int q = 0; q < 4; ++q) {
                int row = q0 + m * 16 + g * 4 + q;
                const int* mrow = mbase + (size_t)row * SS + kt * 64 + l15;
                float s0 = mrow[0]  ? sc[m][0][q] * 0.125f : -1e9f;
                float s1 = mrow[16] ? sc[m][1][q] * 0.125f : -1e9f;
                float s2 = mrow[32] ? sc[m][2][q] * 0.125f : -1e9f;
                float s3 = mrow[48] ? sc[m][3][q] * 0.125f : -1e9f;
                float rm = fmaxf(fmaxf(s0, s1), fmaxf(s2, s3));
                #pragma unroll
                for (int d = 1; d < 16; d <<= 1) rm = fmaxf(rm, __shfl_xor(rm, d, 64));
                float mn = fmaxf(mrun[m][q], rm);
                float ps = __expf(s0 - mn) + __expf(s1 - mn) +
                           __expf(s2 - mn) + __expf(s3 - mn);
                #pragma unroll
                for (int d = 1; d < 16; d <<= 1) ps += __shfl_xor(ps, d, 64);
                lrun[m][q] = lrun[m][q] * __expf(mrun[m][q] - mn) + ps;
                mrun[m][q] = mn;
            }
        __syncthreads();
    }
    float linv[2][4];
    #pragma unroll
    for (int m = 0; m < 2; ++m)
        #pragma unroll
        for (int q = 0; q < 4; ++q) linv[m][q] = 1.0f / lrun[m][q];

    // ---------------- PASS B: P write + O accumulate ----------------
    f32x4 oacc[2][4] = {};
    for (int kt = 0; kt < 32; ++kt) {
        #pragma unroll
        for (int r = 0; r < 2; ++r) {
            size_t gs = ((size_t)bh * SS + kt * 64 + srow[r]) * DEP + sko[r];
            size_t gv = ((size_t)bh * DEP + srow[r]) * SS + kt * 64 + sko[r];
            gll16(Kh + gs, (char*)Ksh + ldso[r]);
            gll16(Kl + gs, (char*)Ksl + ldso[r]);
            gll16(Vh + gv, (char*)Vsh + ldso[r]);
            gll16(Vl + gv, (char*)Vsl + ldso[r]);
        }
        __syncthreads();
        f32x4 sc[2][4] = {};
        #pragma unroll
        for (int ks = 0; ks < 2; ++ks)
            #pragma unroll
            for (int n = 0; n < 4; ++n) {
                short8 kbh = *(const short8*)((const char*)Ksh + kfo[ks][n]);
                short8 kbl = *(const short8*)((const char*)Ksl + kfo[ks][n]);
                #pragma unroll
                for (int m = 0; m < 2; ++m) {
                    sc[m][n] = MFMA_BF16(qfh[m][ks], kbh, sc[m][n], 0, 0, 0);
                    sc[m][n] = MFMA_BF16(qfl[m][ks], kbh, sc[m][n], 0, 0, 0);
                    sc[m][n] = MFMA_BF16(qfh[m][ks], kbl, sc[m][n], 0, 0, 0);
                }
            }
        // P = exp(s - m) / l ; write attn; deposit bf16 hi/lo into LDS
        #pragma unroll
        for (int m = 0; m < 2; ++m)
            #pragma unroll
            for (int q = 0; q < 4; ++q) {
                int row = q0 + m * 16 + g * 4 + q;
                const int* mrow = mbase + (size_t)row * SS + kt * 64 + l15;
                float* arow = attn + ((size_t)bh * SS + row) * SS + kt * 64 + l15;
                int qloc = m * 16 + g * 4 + q;
                #pragma unroll
                for (int n = 0; n < 4; ++n) {
                    float sv = mrow[n * 16] ? sc[m][n][q] * 0.125f : -1e9f;
                    float p  = __expf(sv - mrun[m][q]) * linv[m][q];
                    arow[n * 16] = p;
                    unsigned short ph = f2bf(p);
                    unsigned short pl = f2bf(p - bf2f(ph));
                    int po = swz(qloc * 128 + (n * 16 + l15) * 2);
                    *(unsigned short*)((char*)Psh[wid] + po) = ph;
                    *(unsigned short*)((char*)Psl[wid] + po) = pl;
                }
            }
        // O += P @ V
        #pragma unroll
        for (int ks = 0; ks < 2; ++ks) {
            short8 pah[2], pal[2];
            #pragma unroll
            for (int m = 0; m < 2; ++m) {
                pah[m] = *(const short8*)((const char*)Psh[wid] + pfo[ks][m]);
                pal[m] = *(const short8*)((const char*)Psl[wid] + pfo[ks][m]);
            }
            #pragma unroll
            for (int n = 0; n < 4; ++n) {
                short8 vbh = *(const short8*)((const char*)Vsh + kfo[ks][n]);
                short8 vbl = *(const short8*)((const char*)Vsl + kfo[ks][n]);
                #pragma unroll
                for (int m = 0; m < 2; ++m) {
                    oacc[m][n] = MFMA_BF16(pah[m], vbh, oacc[m][n], 0, 0, 0);
                    oacc[m][n] = MFMA_BF16(pal[m], vbh, oacc[m][n], 0, 0, 0);
                    oacc[m][n] = MFMA_BF16(pah[m], vbl, oacc[m][n], 0, 0, 0);
                }
            }
        }
        __syncthreads();
    }
    // epilogue: ctx[b,s,h*64+d] as bf16 hi/lo
    #pragma unroll
    for (int m = 0; m < 2; ++m)
        #pragma unroll
        for (int n = 0; n < 4; ++n)
            #pragma unroll
            for (int q = 0; q < 4; ++q) {
                int row = q0 + m * 16 + g * 4 + q;
                int col = h_ * 64 + n * 16 + l15;
                size_t idx = ((size_t)(b_ * SS + row)) * DM + col;
                float v = oacc[m][n][q];
                unsigned short hb = f2bf(v);
                ctxh[idx] = hb;
                ctxl[idx] = f2bf(v - bf2f(hb));
            }
}

// ---------------------------------------------------------------------------
extern "C" void kernel_launch(void* const* d_in, const int* in_sizes, int n_in,
                              void* d_out, int out_size, void* d_ws, size_t ws_size,
                              hipStream_t stream) {
    const float* query = (const float*)d_in[0];
    const float* key_  = (const float*)d_in[1];
    const float* value = (const float*)d_in[2];
    const int*   mask  = (const int*)  d_in[3];
    const float* Wq = (const float*)d_in[4];  const float* bq = (const float*)d_in[5];
    const float* Wk = (const float*)d_in[6];  const float* bk = (const float*)d_in[7];
    const float* Wv = (const float*)d_in[8];  const float* bv = (const float*)d_in[9];
    const float* Wo = (const float*)d_in[10]; const float* bo = (const float*)d_in[11];

    float* outp = (float*)d_out;                       // [4096,1024]
    float* attn = outp + (size_t)ROWS * DM;            // [2,16,2048,2048]

    // ws scratch (55 MB; R1 proved >= 67 MB available)
    unsigned short* Qh   = (unsigned short*)d_ws;
    unsigned short* Ql   = Qh   + 4194304;
    unsigned short* Kh   = Ql   + 4194304;
    unsigned short* Kl   = Kh   + 4194304;
    unsigned short* ctxh = Kl   + 4194304;
    unsigned short* ctxl = ctxh + 4194304;
    unsigned short* Wtoh = ctxl + 4194304;
    unsigned short* Wtol = Wtoh + 1048576;
    // scratch inside attn region (dead before attn_fused runs)
    unsigned short* Xh  = (unsigned short*)attn;
    unsigned short* Xl  = Xh  + 4194304;
    unsigned short* Wth = Xl  + 4194304;
    unsigned short* Wtl = Wth + 1048576;
    float*          Vf  = (float*)(Wtl + 1048576);
    // scratch inside out region (dead before final GEMM runs)
    unsigned short* Vth = (unsigned short*)outp;
    unsigned short* Vtl = Vth + 4194304;

    const int n4x = ROWS * DM / 4;
    dim3 cg(4096), wg(16, 16), gg(32, 8), vg(32, 32), ag(16, 32);

    // Wo transpose first (into ws, survives attn)
    convwt<<<wg, 256, 0, stream>>>(Wo, Wtoh, Wtol);
    // Q projection
    convx <<<cg, 256, 0, stream>>>(query, Xh, Xl, n4x);
    convwt<<<wg, 256, 0, stream>>>(Wq, Wth, Wtl);
    gemm_split<<<gg, 256, 0, stream>>>(Xh, Xl, Wth, Wtl, bq, nullptr, Qh, Ql, 1);
    // K projection
    convx <<<cg, 256, 0, stream>>>(key_, Xh, Xl, n4x);
    convwt<<<wg, 256, 0, stream>>>(Wk, Wth, Wtl);
    gemm_split<<<gg, 256, 0, stream>>>(Xh, Xl, Wth, Wtl, bk, nullptr, Kh, Kl, 1);
    // V projection (fp32 head layout, then transpose-convert)
    convx <<<cg, 256, 0, stream>>>(value, Xh, Xl, n4x);
    convwt<<<wg, 256, 0, stream>>>(Wv, Wth, Wtl);
    gemm_split<<<gg, 256, 0, stream>>>(Xh, Xl, Wth, Wtl, bv, Vf, nullptr, nullptr, 2);
    convvt<<<vg, 256, 0, stream>>>(Vf, Vth, Vtl);
    // fused attention: writes attn + ctx
    attn_fused<<<ag, 256, 0, stream>>>(Qh, Ql, Kh, Kl, Vth, Vtl, mask, attn, ctxh, ctxl);
    // output projection
    gemm_split<<<gg, 256, 0, stream>>>(ctxh, ctxl, Wtoh, Wtol, bo, outp, nullptr, nullptr, 0);
}